// Round 1
// baseline (16000.685 us; speedup 1.0000x reference)
//
#include <hip/hip_runtime.h>

#define H_ 1024
#define B_ 128
#define S_ 512
#define V_ 128
#define E_ 256

#define BSH_ROW 1032            // 1024 + 8 pad (bf16 elems)
#define ASH_ROW 72              // 64 + 8 pad
#define ZSH_ROW 36              // 32 + 4 pad (f32)
#define BSH_BYTES (32 * BSH_ROW * 2)     // 66048
#define ASH_BYTES (2 * 128 * ASH_ROW * 2) // 36864
#define ZSH_BYTES (128 * ZSH_ROW * 4)     // 18432
#define SMEM_TOTAL (BSH_BYTES + ASH_BYTES + ZSH_BYTES + 512) // 121856

typedef __bf16 bf16x8 __attribute__((ext_vector_type(8)));
typedef float f32x4 __attribute__((ext_vector_type(4)));

__device__ __forceinline__ unsigned short f2bf(float f) {
  unsigned u = __float_as_uint(f);
  u += 0x7fffu + ((u >> 16) & 1u);   // round-to-nearest-even
  return (unsigned short)(u >> 16);
}
__device__ __forceinline__ float sigf(float x) { return 1.0f / (1.0f + __expf(-x)); }
__device__ __forceinline__ float tanhfast(float x) { return 1.0f - 2.0f / (1.0f + __expf(2.0f * x)); }

// ---- device-scope grid barrier (monotonic counter, no reset) ----
__device__ __forceinline__ void gbar(unsigned* cnt, unsigned target) {
  __threadfence();      // release own stores at agent scope
  __syncthreads();
  if (threadIdx.x == 0) {
    __hip_atomic_fetch_add(cnt, 1u, __ATOMIC_RELEASE, __HIP_MEMORY_SCOPE_AGENT);
    while (__hip_atomic_load(cnt, __ATOMIC_RELAXED, __HIP_MEMORY_SCOPE_AGENT) < target) {
      __builtin_amdgcn_s_sleep(1);
    }
    __threadfence();    // acquire: invalidate L1/L2 before reading others' h
  }
  __syncthreads();
}

// ---- tokproj[v][c] = emb[v]@Wx_gate + bias ; c = gate*1024 + j ----
__global__ void __launch_bounds__(256)
tokproj_kernel(const float* __restrict__ emb,
               const float* __restrict__ Wgx, const float* __restrict__ Wix,
               const float* __restrict__ Wfx, const float* __restrict__ Wox,
               const float* __restrict__ bg, const float* __restrict__ bi,
               const float* __restrict__ bf_, const float* __restrict__ bo,
               float* __restrict__ tokproj) {
  __shared__ float esh[E_];
  const int v = blockIdx.x;
  const int c = blockIdx.y * 256 + threadIdx.x;
  const int gate = c >> 10;
  const int j = c & 1023;
  const float* W = (gate == 0) ? Wgx : (gate == 1) ? Wix : (gate == 2) ? Wfx : Wox;
  const float* bias = (gate == 0) ? bg : (gate == 1) ? bi : (gate == 2) ? bf_ : bo;
  esh[threadIdx.x] = emb[v * E_ + threadIdx.x];
  __syncthreads();
  float acc = bias[j];
#pragma unroll 4
  for (int e = 0; e < E_; ++e) acc += esh[e] * W[e * H_ + j];
  tokproj[v * 4096 + c] = acc;
}

// ---- WhT[c][k] = bf16(Wh_gate[k][j]) ; c = gate*1024 + j ----
__global__ void __launch_bounds__(256)
wht_kernel(const float* __restrict__ Wgh, const float* __restrict__ Wih,
           const float* __restrict__ Wfh, const float* __restrict__ Woh,
           unsigned short* __restrict__ WhT) {
  const int c = blockIdx.x;
  const int gate = c >> 10;
  const int j = c & 1023;
  const float* W = (gate == 0) ? Wgh : (gate == 1) ? Wih : (gate == 2) ? Wfh : Woh;
  for (int k = threadIdx.x; k < H_; k += 256)
    WhT[c * H_ + k] = f2bf(W[k * H_ + j]);
}

// ---- persistent scan: 128 blocks x 256 thr; block n owns hidden [n*8, n*8+8) ----
__global__ void __launch_bounds__(256)
lstm_scan(const int* __restrict__ x, const float* __restrict__ tokproj,
          const unsigned short* __restrict__ WhT,
          unsigned short* __restrict__ hbuf, float* __restrict__ hfin,
          unsigned* __restrict__ cnt) {
  extern __shared__ char smem[];
  unsigned short* Bsh = (unsigned short*)smem;                          // [32][1032] bf16
  unsigned short* Ash = (unsigned short*)(smem + BSH_BYTES);            // [2][128][72] bf16
  float* Zsh = (float*)(smem + BSH_BYTES + ASH_BYTES);                  // [128][36] f32
  int* xsh = (int*)(smem + BSH_BYTES + ASH_BYTES + ZSH_BYTES);          // [128]

  const int n = blockIdx.x;
  const int tid = threadIdx.x;
  const int wave = tid >> 6;
  const int lane = tid & 63;
  const int l15 = lane & 15;
  const int lq = lane >> 4;

  // Load this block's 32 WhT rows (gate-major: j = gate*8 + hu) into LDS once.
  for (int it = tid; it < 4096; it += 256) {
    int j = it >> 7;
    int ko = (it & 127) << 3;
    int c = ((j >> 3) << 10) + n * 8 + (j & 7);
    *(uint4*)(Bsh + j * BSH_ROW + ko) = *(const uint4*)(WhT + c * 1024 + ko);
  }

  const int b_own = tid >> 1;        // batch row this thread owns in gate pass
  const int hu0 = (tid & 1) << 2;    // first of 4 hidden units
  const int col0 = n * 8 + hu0;      // global h column

  float creg[4] = {0.f, 0.f, 0.f, 0.f};
  *(unsigned long long*)(hbuf + b_own * H_ + col0) = 0ull;  // zero h^{-1} (buf 0)

  unsigned phase = 1;
  gbar(cnt, phase * 128u);

  // staging geometry: thread covers row srow (+r*32), 16B chunk at sko
  const int srow = tid >> 3;
  const int sko = (tid & 7) << 3;
  // fragment offsets (bf16 elems)
  const int aoff0 = (wave * 32 + l15) * ASH_ROW + lq * 8;
  const int aoff1 = aoff0 + 16 * ASH_ROW;
  const int boff0 = l15 * BSH_ROW + lq * 8;
  const int boff1 = boff0 + 16 * BSH_ROW;

  for (int s = 0; s < S_; ++s) {
    const unsigned short* rd = hbuf + (s & 1) * (B_ * H_);
    unsigned short* wr = hbuf + ((s + 1) & 1) * (B_ * H_);

    if (tid < 128) xsh[tid] = x[tid * S_ + s];

    f32x4 acc00 = {0.f, 0.f, 0.f, 0.f}, acc01 = {0.f, 0.f, 0.f, 0.f};
    f32x4 acc10 = {0.f, 0.f, 0.f, 0.f}, acc11 = {0.f, 0.f, 0.f, 0.f};

    uint4 pre[4];
#pragma unroll
    for (int r = 0; r < 4; ++r)
      pre[r] = *(const uint4*)(rd + (r * 32 + srow) * H_ + sko);
#pragma unroll
    for (int r = 0; r < 4; ++r)
      *(uint4*)(Ash + (r * 32 + srow) * ASH_ROW + sko) = pre[r];
    __syncthreads();

    for (int kt = 0; kt < 16; ++kt) {
      const unsigned short* Abase = Ash + (kt & 1) * (128 * ASH_ROW);
      if (kt < 15) {
        const int k0n = (kt + 1) << 6;
#pragma unroll
        for (int r = 0; r < 4; ++r)
          pre[r] = *(const uint4*)(rd + (r * 32 + srow) * H_ + k0n + sko);
      }
#pragma unroll
      for (int kc = 0; kc < 64; kc += 32) {
        bf16x8 a0 = *(const bf16x8*)(Abase + aoff0 + kc);
        bf16x8 a1 = *(const bf16x8*)(Abase + aoff1 + kc);
        const int kb = (kt << 6) + kc;
        bf16x8 b0 = *(const bf16x8*)(Bsh + boff0 + kb);
        bf16x8 b1 = *(const bf16x8*)(Bsh + boff1 + kb);
        acc00 = __builtin_amdgcn_mfma_f32_16x16x32_bf16(a0, b0, acc00, 0, 0, 0);
        acc01 = __builtin_amdgcn_mfma_f32_16x16x32_bf16(a0, b1, acc01, 0, 0, 0);
        acc10 = __builtin_amdgcn_mfma_f32_16x16x32_bf16(a1, b0, acc10, 0, 0, 0);
        acc11 = __builtin_amdgcn_mfma_f32_16x16x32_bf16(a1, b1, acc11, 0, 0, 0);
      }
      if (kt < 15) {
        unsigned short* dstA = Ash + ((kt + 1) & 1) * (128 * ASH_ROW);
#pragma unroll
        for (int r = 0; r < 4; ++r)
          *(uint4*)(dstA + (r * 32 + srow) * ASH_ROW + sko) = pre[r];
      }
      __syncthreads();
    }

    // C/D layout: col = lane&15, row = (lane>>4)*4 + reg
#pragma unroll
    for (int r = 0; r < 4; ++r) {
      int m0 = wave * 32 + lq * 4 + r;
      Zsh[m0 * ZSH_ROW + l15] = acc00[r];
      Zsh[m0 * ZSH_ROW + 16 + l15] = acc01[r];
      Zsh[(m0 + 16) * ZSH_ROW + l15] = acc10[r];
      Zsh[(m0 + 16) * ZSH_ROW + 16 + l15] = acc11[r];
    }
    __syncthreads();

    // gate pass: thread owns (b_own, hu0..hu0+3)
    {
      const int xb = xsh[b_own];
      const float* tp = tokproj + xb * 4096 + col0;
      float zg[4], zi[4], zf[4], zo[4], tg[4], ti[4], tf2[4], to2[4];
      *(float4*)zg = *(const float4*)(Zsh + b_own * ZSH_ROW + hu0);
      *(float4*)zi = *(const float4*)(Zsh + b_own * ZSH_ROW + 8 + hu0);
      *(float4*)zf = *(const float4*)(Zsh + b_own * ZSH_ROW + 16 + hu0);
      *(float4*)zo = *(const float4*)(Zsh + b_own * ZSH_ROW + 24 + hu0);
      *(float4*)tg = *(const float4*)(tp);
      *(float4*)ti = *(const float4*)(tp + 1024);
      *(float4*)tf2 = *(const float4*)(tp + 2048);
      *(float4*)to2 = *(const float4*)(tp + 3072);
      float hv[4];
#pragma unroll
      for (int q = 0; q < 4; ++q) {
        float g = tanhfast(zg[q] + tg[q]);
        float iv = sigf(zi[q] + ti[q]);
        float fv = sigf(zf[q] + tf2[q]);
        float ov = sigf(zo[q] + to2[q]);
        creg[q] = g * iv + creg[q] * fv;
        hv[q] = tanhfast(creg[q]) * ov;
      }
      unsigned long long hp = (unsigned long long)f2bf(hv[0])
          | ((unsigned long long)f2bf(hv[1]) << 16)
          | ((unsigned long long)f2bf(hv[2]) << 32)
          | ((unsigned long long)f2bf(hv[3]) << 48);
      *(unsigned long long*)(wr + b_own * H_ + col0) = hp;
      if (s == S_ - 1) {
        float4 h4;
        h4.x = hv[0]; h4.y = hv[1]; h4.z = hv[2]; h4.w = hv[3];
        *(float4*)(hfin + b_own * H_ + col0) = h4;
      }
    }
    ++phase;
    gbar(cnt, phase * 128u);
  }
}

// ---- p = hfin @ W_ph + b_p ; out = log_softmax(p) ----
__global__ void __launch_bounds__(256)
classify_kernel(const float* __restrict__ hfin, const float* __restrict__ Wph,
                const float* __restrict__ bp, float* __restrict__ out) {
  __shared__ float red[256 * 10];
  const int b = blockIdx.x, tid = threadIdx.x;
  float acc[10];
#pragma unroll
  for (int c = 0; c < 10; ++c) acc[c] = 0.f;
  for (int k = tid; k < H_; k += 256) {
    const float hv = hfin[b * H_ + k];
    const float* w = Wph + k * 10;
#pragma unroll
    for (int c = 0; c < 10; ++c) acc[c] += hv * w[c];
  }
#pragma unroll
  for (int c = 0; c < 10; ++c) red[tid * 10 + c] = acc[c];
  __syncthreads();
  for (int off = 128; off >= 1; off >>= 1) {
    if (tid < off) {
#pragma unroll
      for (int c = 0; c < 10; ++c) red[tid * 10 + c] += red[(tid + off) * 10 + c];
    }
    __syncthreads();
  }
  if (tid == 0) {
    float p[10];
    float m = -1e30f;
#pragma unroll
    for (int c = 0; c < 10; ++c) { p[c] = red[c] + bp[c]; m = fmaxf(m, p[c]); }
    float ssum = 0.f;
#pragma unroll
    for (int c = 0; c < 10; ++c) ssum += __expf(p[c] - m);
    const float lse = m + __logf(ssum);
#pragma unroll
    for (int c = 0; c < 10; ++c) out[b * 10 + c] = p[c] - lse;
  }
}

extern "C" void kernel_launch(void* const* d_in, const int* in_sizes, int n_in,
                              void* d_out, int out_size, void* d_ws, size_t ws_size,
                              hipStream_t stream) {
  (void)in_sizes; (void)n_in; (void)out_size; (void)ws_size;
  const int* x = (const int*)d_in[0];
  const float* emb = (const float*)d_in[1];
  const float* Wgx = (const float*)d_in[2];
  const float* Wgh = (const float*)d_in[3];
  const float* bg = (const float*)d_in[4];
  const float* Wix = (const float*)d_in[5];
  const float* Wih = (const float*)d_in[6];
  const float* bi = (const float*)d_in[7];
  const float* Wfx = (const float*)d_in[8];
  const float* Wfh = (const float*)d_in[9];
  const float* bf_ = (const float*)d_in[10];
  const float* Wox = (const float*)d_in[11];
  const float* Woh = (const float*)d_in[12];
  const float* bo = (const float*)d_in[13];
  const float* Wph = (const float*)d_in[14];
  const float* bp = (const float*)d_in[15];
  float* out = (float*)d_out;

  char* ws = (char*)d_ws;
  float* tokproj = (float*)ws;                                  // 2 MB
  unsigned short* WhT = (unsigned short*)(ws + 2097152);        // 8 MB
  unsigned short* hbuf = (unsigned short*)(ws + 10485760);      // 512 KB (2 bufs)
  float* hfin = (float*)(ws + 11010048);                        // 512 KB
  unsigned* cnt = (unsigned*)(ws + 11534336);                   // 4 B

  hipMemsetAsync(cnt, 0, 4, stream);
  hipFuncSetAttribute(reinterpret_cast<const void*>(lstm_scan),
                      hipFuncAttributeMaxDynamicSharedMemorySize, SMEM_TOTAL);

  tokproj_kernel<<<dim3(V_, 16), dim3(256), 0, stream>>>(
      emb, Wgx, Wix, Wfx, Wox, bg, bi, bf_, bo, tokproj);
  wht_kernel<<<dim3(4096), dim3(256), 0, stream>>>(Wgh, Wih, Wfh, Woh, WhT);
  lstm_scan<<<dim3(128), dim3(256), SMEM_TOTAL, stream>>>(
      x, tokproj, WhT, hbuf, hfin, cnt);
  classify_kernel<<<dim3(128), dim3(256), 0, stream>>>(hfin, Wph, bp, out);
}